// Round 1
// baseline (14436.801 us; speedup 1.0000x reference)
//
#include <hip/hip_runtime.h>
#include <hip/hip_bf16.h>

#define TT 2048
#define BB 32
#define DD 256
#define HH 256
#define GG 768   // 3*H

// ---------- helpers for fp32/bf16 workspace storage of gi ----------
__device__ inline void store4(float* p, float a, float b, float c, float d) {
    *(float4*)p = make_float4(a, b, c, d);
}
__device__ inline void store4(__hip_bfloat16* p, float a, float b, float c, float d) {
    p[0] = __float2bfloat16(a);
    p[1] = __float2bfloat16(b);
    p[2] = __float2bfloat16(c);
    p[3] = __float2bfloat16(d);
}
__device__ inline float ldgi(const float* p) { return *p; }
__device__ inline float ldgi(const __hip_bfloat16* p) { return __bfloat162float(*p); }

// ---------- transpose w_hh [768][256] -> wT [256][768] ----------
__global__ __launch_bounds__(256)
void transpose_w(const float* __restrict__ w, float* __restrict__ wt) {
    __shared__ float t[32][33];
    int bx = blockIdx.x * 32;  // k dim (0..255)
    int by = blockIdx.y * 32;  // j dim (0..767)
    int x = threadIdx.x;       // 0..31
    int y = threadIdx.y;       // 0..7
    for (int yy = y; yy < 32; yy += 8)
        t[yy][x] = w[(size_t)(by + yy) * DD + bx + x];
    __syncthreads();
    for (int yy = y; yy < 32; yy += 8)
        wt[(size_t)(bx + yy) * GG + by + x] = t[x][yy];
}

// ---------- gi = seq @ w_ih^T + b_ih ; M=65536, N=768, K=256 ----------
template <typename GiT>
__global__ __launch_bounds__(256)
void gemm_gi(const float* __restrict__ A,     // [M][256]
             const float* __restrict__ W,     // [768][256]
             const float* __restrict__ bias,  // [768]
             GiT* __restrict__ C)              // [M][768]
{
    __shared__ float As[32][68];  // [k][m], stride 272B = 16B-aligned rows
    __shared__ float Ws[32][68];  // [k][n]
    const int tid = threadIdx.x;
    const int bm = blockIdx.y * 64;
    const int bn = blockIdx.x * 64;
    const int tm = (tid & 15) * 4;
    const int tn = (tid >> 4) * 4;
    const int r  = tid >> 3;        // 0..31
    const int c4 = (tid & 7) * 4;   // 0..28

    float acc[4][4] = {};

    for (int k0 = 0; k0 < 256; k0 += 32) {
#pragma unroll
        for (int rr = 0; rr < 64; rr += 32) {
            float4 a = *(const float4*)&A[(size_t)(bm + r + rr) * 256 + k0 + c4];
            As[c4 + 0][r + rr] = a.x;
            As[c4 + 1][r + rr] = a.y;
            As[c4 + 2][r + rr] = a.z;
            As[c4 + 3][r + rr] = a.w;
            float4 w = *(const float4*)&W[(size_t)(bn + r + rr) * 256 + k0 + c4];
            Ws[c4 + 0][r + rr] = w.x;
            Ws[c4 + 1][r + rr] = w.y;
            Ws[c4 + 2][r + rr] = w.z;
            Ws[c4 + 3][r + rr] = w.w;
        }
        __syncthreads();
#pragma unroll
        for (int kk = 0; kk < 32; ++kk) {
            float4 a = *(const float4*)&As[kk][tm];
            float4 w = *(const float4*)&Ws[kk][tn];
            float av[4] = {a.x, a.y, a.z, a.w};
            float wv[4] = {w.x, w.y, w.z, w.w};
#pragma unroll
            for (int i = 0; i < 4; ++i)
#pragma unroll
                for (int j = 0; j < 4; ++j)
                    acc[i][j] += av[i] * wv[j];
        }
        __syncthreads();
    }
#pragma unroll
    for (int i = 0; i < 4; ++i) {
        GiT* cp = C + (size_t)(bm + tm + i) * GG + bn + tn;
        store4(cp, acc[i][0] + bias[bn + tn + 0],
                   acc[i][1] + bias[bn + tn + 1],
                   acc[i][2] + bias[bn + tn + 2],
                   acc[i][3] + bias[bn + tn + 3]);
    }
}

// ---------- sequential scan: 1 workgroup per batch row ----------
template <typename GiT>
__global__ __launch_bounds__(768)
void gru_scan(const GiT* __restrict__ gi,     // [T*B][768]
              const int* __restrict__ mask,    // [T*B]
              const float* __restrict__ h0,    // [B][256]
              const float* __restrict__ wT,    // [256][768]
              const float* __restrict__ b_hh,  // [768]
              float* __restrict__ out,         // [T*B][256]
              float* __restrict__ hfin)        // [B][256]
{
    const int b = blockIdx.x;
    const int j = threadIdx.x;  // 0..767
    __shared__ __align__(16) float h_lds[HH];
    __shared__ float gh_lds[GG];

    if (j < HH) h_lds[j] = h0[b * HH + j];
    const float bhh = b_hh[j];
    __syncthreads();

    const float4* h4 = (const float4*)h_lds;

    for (int t = 0; t < TT; ++t) {
        // issue gi + mask loads early; consumed after the barrier (latency
        // hidden under the 256-FMA GEMV below)
        int m = mask[t * BB + b];
        float ir = 0.f, iz = 0.f, inn = 0.f;
        if (j < HH) {
            const GiT* gtb = gi + ((size_t)t * BB + b) * GG;
            ir  = ldgi(gtb + j);
            iz  = ldgi(gtb + j + HH);
            inn = ldgi(gtb + j + 2 * HH);
        }

        // gh[j] = b_hh[j] + sum_k wT[k][j] * h[k]
        float g = bhh;
#pragma unroll 8
        for (int k4 = 0; k4 < HH / 4; ++k4) {
            float4 hv = h4[k4];
            const float* wp = wT + (size_t)(k4 * 4) * GG + j;
            g += wp[0 * GG] * hv.x;
            g += wp[1 * GG] * hv.y;
            g += wp[2 * GG] * hv.z;
            g += wp[3 * GG] * hv.w;
        }
        gh_lds[j] = g;
        __syncthreads();

        if (j < HH) {
            float hr = gh_lds[j];
            float hz = gh_lds[j + HH];
            float hn = gh_lds[j + 2 * HH];
            float r = 1.f / (1.f + __expf(-(ir + hr)));
            float z = 1.f / (1.f + __expf(-(iz + hz)));
            // tanh(y) = 1 - 2/(exp(2y)+1)  (saturates correctly at +/-inf)
            float e = __expf(2.f * (inn + r * hn));
            float n = 1.f - 2.f / (e + 1.f);
            float h = h_lds[j];
            float ht = (1.f - z) * n + z * h;
            out[((size_t)t * BB + b) * HH + j] = m ? ht : 0.f;
            h_lds[j] = m ? ht : h;
        }
        __syncthreads();
    }
    if (j < HH) hfin[b * HH + j] = h_lds[j];
}

extern "C" void kernel_launch(void* const* d_in, const int* in_sizes, int n_in,
                              void* d_out, int out_size, void* d_ws, size_t ws_size,
                              hipStream_t stream) {
    const float* seq  = (const float*)d_in[0];
    const int*   mask = (const int*)  d_in[1];
    const float* h0   = (const float*)d_in[2];
    const float* w_ih = (const float*)d_in[3];
    const float* w_hh = (const float*)d_in[4];
    const float* b_ih = (const float*)d_in[5];
    const float* b_hh = (const float*)d_in[6];

    float* out  = (float*)d_out;
    float* hfin = out + (size_t)TT * BB * HH;

    // workspace layout: [wT: 256*768 f32][gi: T*B*768 f32 (or bf16 fallback)]
    const size_t wt_elems = (size_t)DD * GG;
    float* wt = (float*)d_ws;
    const size_t gi_elems = (size_t)TT * BB * GG;
    const size_t need_f32 = wt_elems * 4 + gi_elems * 4;

    transpose_w<<<dim3(8, 24), dim3(32, 8), 0, stream>>>(w_hh, wt);

    dim3 ggrid(GG / 64, (TT * BB) / 64);
    if (ws_size >= need_f32) {
        float* gi = (float*)d_ws + wt_elems;
        gemm_gi<float><<<ggrid, 256, 0, stream>>>(seq, w_ih, b_ih, gi);
        gru_scan<float><<<BB, GG, 0, stream>>>(gi, mask, h0, wt, b_hh, out, hfin);
    } else {
        __hip_bfloat16* gi = (__hip_bfloat16*)((float*)d_ws + wt_elems);
        gemm_gi<__hip_bfloat16><<<ggrid, 256, 0, stream>>>(seq, w_ih, b_ih, gi);
        gru_scan<__hip_bfloat16><<<BB, GG, 0, stream>>>(gi, mask, h0, wt, b_hh, out, hfin);
    }
}

// Round 2
// 2916.004 us; speedup vs baseline: 4.9509x; 4.9509x over previous
//
#include <hip/hip_runtime.h>
#include <hip/hip_bf16.h>

#define TT 2048
#define BB 32
#define DD 256
#define HH 256
#define GG 768   // 3*H

typedef _Float16 half2_t __attribute__((ext_vector_type(2)));

__device__ inline float fdot2(unsigned int w, unsigned int h, float acc) {
#if __has_builtin(__builtin_amdgcn_fdot2)
    return __builtin_amdgcn_fdot2(__builtin_bit_cast(half2_t, w),
                                  __builtin_bit_cast(half2_t, h), acc, false);
#else
    half2_t a = __builtin_bit_cast(half2_t, w);
    half2_t b = __builtin_bit_cast(half2_t, h);
    return acc + (float)a.x * (float)b.x + (float)a.y * (float)b.y;
#endif
}

// ---------- helpers for fp32/bf16 workspace storage of gi ----------
__device__ inline void store4(float* p, float a, float b, float c, float d) {
    *(float4*)p = make_float4(a, b, c, d);
}
__device__ inline void store4(__hip_bfloat16* p, float a, float b, float c, float d) {
    p[0] = __float2bfloat16(a);
    p[1] = __float2bfloat16(b);
    p[2] = __float2bfloat16(c);
    p[3] = __float2bfloat16(d);
}
__device__ inline float ldgi(const float* p) { return *p; }
__device__ inline float ldgi(const __hip_bfloat16* p) { return __bfloat162float(*p); }

// ---------- pack w_hh [768][256] f32 -> wpk [128][768] of f16x2 ----------
// wpk[q][j] = (f16(w_hh[j][2q]), f16(w_hh[j][2q+1]))
__global__ __launch_bounds__(256)
void pack_w(const float* __restrict__ w, unsigned int* __restrict__ wpk) {
    int i = blockIdx.x * 256 + threadIdx.x;  // 0 .. 98303
    int q = i / GG;
    int j = i - q * GG;
    float a = w[(size_t)j * DD + 2 * q];
    float b = w[(size_t)j * DD + 2 * q + 1];
    half2_t h = {(_Float16)a, (_Float16)b};
    wpk[i] = __builtin_bit_cast(unsigned int, h);
}

// ---------- gi = seq @ w_ih^T + b_ih ; M=65536, N=768, K=256 ----------
template <typename GiT>
__global__ __launch_bounds__(256)
void gemm_gi(const float* __restrict__ A,     // [M][256]
             const float* __restrict__ W,     // [768][256]
             const float* __restrict__ bias,  // [768]
             GiT* __restrict__ C)              // [M][768]
{
    __shared__ float As[32][68];
    __shared__ float Ws[32][68];
    const int tid = threadIdx.x;
    const int bm = blockIdx.y * 64;
    const int bn = blockIdx.x * 64;
    const int tm = (tid & 15) * 4;
    const int tn = (tid >> 4) * 4;
    const int r  = tid >> 3;
    const int c4 = (tid & 7) * 4;

    float acc[4][4] = {};

    for (int k0 = 0; k0 < 256; k0 += 32) {
#pragma unroll
        for (int rr = 0; rr < 64; rr += 32) {
            float4 a = *(const float4*)&A[(size_t)(bm + r + rr) * 256 + k0 + c4];
            As[c4 + 0][r + rr] = a.x;
            As[c4 + 1][r + rr] = a.y;
            As[c4 + 2][r + rr] = a.z;
            As[c4 + 3][r + rr] = a.w;
            float4 w = *(const float4*)&W[(size_t)(bn + r + rr) * 256 + k0 + c4];
            Ws[c4 + 0][r + rr] = w.x;
            Ws[c4 + 1][r + rr] = w.y;
            Ws[c4 + 2][r + rr] = w.z;
            Ws[c4 + 3][r + rr] = w.w;
        }
        __syncthreads();
#pragma unroll
        for (int kk = 0; kk < 32; ++kk) {
            float4 a = *(const float4*)&As[kk][tm];
            float4 w = *(const float4*)&Ws[kk][tn];
            float av[4] = {a.x, a.y, a.z, a.w};
            float wv[4] = {w.x, w.y, w.z, w.w};
#pragma unroll
            for (int i = 0; i < 4; ++i)
#pragma unroll
                for (int j = 0; j < 4; ++j)
                    acc[i][j] += av[i] * wv[j];
        }
        __syncthreads();
    }
#pragma unroll
    for (int i = 0; i < 4; ++i) {
        GiT* cp = C + (size_t)(bm + tm + i) * GG + bn + tn;
        store4(cp, acc[i][0] + bias[bn + tn + 0],
                   acc[i][1] + bias[bn + tn + 1],
                   acc[i][2] + bias[bn + tn + 2],
                   acc[i][3] + bias[bn + tn + 3]);
    }
}

// ---------- sequential scan: 1 workgroup per batch row ----------
// Thread j holds w_hh row j (256 weights) as 128 packed f16x2 in VGPRs.
template <typename GiT>
__global__ __launch_bounds__(768)
void gru_scan(const GiT* __restrict__ gi,          // [T*B][768]
              const int* __restrict__ mask,         // [T*B]
              const float* __restrict__ h0,         // [B][256]
              const unsigned int* __restrict__ wpk, // [128][768] f16x2
              const float* __restrict__ b_hh,       // [768]
              float* __restrict__ out,              // [T*B][256]
              float* __restrict__ hfin)             // [B][256]
{
    const int b = blockIdx.x;
    const int j = threadIdx.x;  // 0..767
    __shared__ float h_lds[HH];                   // fp32 state
    __shared__ __align__(16) _Float16 hhalf[HH];  // f16 copy for the GEMV
    __shared__ float gh_lds[GG];
    __shared__ int mask_lds[TT];

    // --- one-time preloads ---
    unsigned int w[128];
#pragma unroll
    for (int q = 0; q < 128; ++q)
        w[q] = wpk[q * GG + j];  // coalesced across lanes

    for (int t = j; t < TT; t += GG)
        mask_lds[t] = mask[t * BB + b];

    if (j < HH) {
        float h = h0[b * HH + j];
        h_lds[j] = h;
        hhalf[j] = (_Float16)h;
    }
    const float bhh = b_hh[j];

    // preload gi + mask for t=0
    float ir = 0.f, iz = 0.f, inn = 0.f;
    if (j < HH) {
        const GiT* g0 = gi + (size_t)b * GG;
        ir  = ldgi(g0 + j);
        iz  = ldgi(g0 + j + HH);
        inn = ldgi(g0 + j + 2 * HH);
    }
    __syncthreads();
    int m = mask_lds[0];

    const uint4* hu4 = (const uint4*)hhalf;

    for (int t = 0; t < TT; ++t) {
        // --- GEMV: gh[j] = b_hh[j] + sum_k w_hh[j][k] * h[k] ---
        float a0 = bhh, a1 = 0.f, a2 = 0.f, a3 = 0.f;
#pragma unroll
        for (int q4 = 0; q4 < 32; ++q4) {
            uint4 hv = hu4[q4];  // wave-uniform -> LDS broadcast
            a0 = fdot2(w[4 * q4 + 0], hv.x, a0);
            a1 = fdot2(w[4 * q4 + 1], hv.y, a1);
            a2 = fdot2(w[4 * q4 + 2], hv.z, a2);
            a3 = fdot2(w[4 * q4 + 3], hv.w, a3);
        }
        gh_lds[j] = (a0 + a1) + (a2 + a3);

        // --- issue gi loads for t+1 (latency hidden across gate phase) ---
        int tn = (t + 1 < TT) ? t + 1 : t;
        float ir2 = 0.f, iz2 = 0.f, inn2 = 0.f;
        if (j < HH) {
            const GiT* gtb = gi + ((size_t)tn * BB + b) * GG;
            ir2  = ldgi(gtb + j);
            iz2  = ldgi(gtb + j + HH);
            inn2 = ldgi(gtb + j + 2 * HH);
        }
        __syncthreads();  // gh visible; all hhalf reads done

        if (j < HH) {
            float hr = gh_lds[j];
            float hz = gh_lds[j + HH];
            float hn = gh_lds[j + 2 * HH];
            float r = 1.f / (1.f + __expf(-(ir + hr)));
            float z = 1.f / (1.f + __expf(-(iz + hz)));
            float e = __expf(2.f * (inn + r * hn));
            float n = 1.f - 2.f / (e + 1.f);
            float h = h_lds[j];
            float ht = (1.f - z) * n + z * h;
            out[((size_t)t * BB + b) * HH + j] = m ? ht : 0.f;
            float hnew = m ? ht : h;
            h_lds[j] = hnew;
            hhalf[j] = (_Float16)hnew;
        }
        ir = ir2; iz = iz2; inn = inn2;
        m = mask_lds[tn];
        __syncthreads();  // h update visible before next GEMV
    }
    if (j < HH) hfin[b * HH + j] = h_lds[j];
}

extern "C" void kernel_launch(void* const* d_in, const int* in_sizes, int n_in,
                              void* d_out, int out_size, void* d_ws, size_t ws_size,
                              hipStream_t stream) {
    const float* seq  = (const float*)d_in[0];
    const int*   mask = (const int*)  d_in[1];
    const float* h0   = (const float*)d_in[2];
    const float* w_ih = (const float*)d_in[3];
    const float* w_hh = (const float*)d_in[4];
    const float* b_ih = (const float*)d_in[5];
    const float* b_hh = (const float*)d_in[6];

    float* out  = (float*)d_out;
    float* hfin = out + (size_t)TT * BB * HH;

    // workspace layout: [wpk: 128*768 u32][gi: T*B*768 f32 (or bf16 fallback)]
    const size_t wpk_elems = (size_t)128 * GG;
    unsigned int* wpk = (unsigned int*)d_ws;
    const size_t gi_elems = (size_t)TT * BB * GG;
    const size_t need_f32 = wpk_elems * 4 + gi_elems * 4;

    pack_w<<<(128 * GG) / 256, 256, 0, stream>>>(w_hh, wpk);

    dim3 ggrid(GG / 64, (TT * BB) / 64);
    if (ws_size >= need_f32) {
        float* gip = (float*)d_ws + wpk_elems;
        gemm_gi<float><<<ggrid, 256, 0, stream>>>(seq, w_ih, b_ih, gip);
        gru_scan<float><<<BB, GG, 0, stream>>>(gip, mask, h0, wpk, b_hh, out, hfin);
    } else {
        __hip_bfloat16* gip = (__hip_bfloat16*)((float*)d_ws + wpk_elems);
        gemm_gi<__hip_bfloat16><<<ggrid, 256, 0, stream>>>(seq, w_ih, b_ih, gip);
        gru_scan<__hip_bfloat16><<<BB, GG, 0, stream>>>(gip, mask, h0, wpk, b_hh, out, hfin);
    }
}

// Round 3
// 2821.585 us; speedup vs baseline: 5.1166x; 1.0335x over previous
//
#include <hip/hip_runtime.h>
#include <hip/hip_bf16.h>

#define TT 2048
#define BB 32
#define DD 256
#define HH 256
#define GG 768   // 3*H
#define NB 2     // batches per scan block

typedef _Float16 f16x8 __attribute__((ext_vector_type(8)));
typedef float    f32x4 __attribute__((ext_vector_type(4)));
typedef unsigned int u32x4 __attribute__((ext_vector_type(4)));
typedef _Float16 half2_t __attribute__((ext_vector_type(2)));

// ---------- helpers for fp32/bf16 workspace storage of gi ----------
__device__ inline void store4(float* p, float a, float b, float c, float d) {
    *(float4*)p = make_float4(a, b, c, d);
}
__device__ inline void store4(__hip_bfloat16* p, float a, float b, float c, float d) {
    p[0] = __float2bfloat16(a);
    p[1] = __float2bfloat16(b);
    p[2] = __float2bfloat16(c);
    p[3] = __float2bfloat16(d);
}
__device__ inline float ldgi(const float* p) { return *p; }
__device__ inline float ldgi(const __hip_bfloat16* p) { return __bfloat162float(*p); }

// ---------- pack w_hh [768][256] f32 into per-wave MFMA B-fragments ----------
// flat u32 index: (((wv*6+nt)*8+kt)*64+l)*4+r
//   n = wv*96 + nt*16 + (l&15)
//   k = kt*32 + (l>>4)*8 + 2r   (u32 = f16 pair {k, k+1}, low half first)
__global__ __launch_bounds__(256)
void pack_w(const float* __restrict__ w, unsigned int* __restrict__ wf) {
    int idx = blockIdx.x * 256 + threadIdx.x;  // 0 .. 98303
    int r    = idx & 3;
    int l    = (idx >> 2) & 63;
    int kt   = (idx >> 8) & 7;
    int rest = idx >> 11;            // wv*6 + nt, 0..47
    int nt = rest % 6, wv = rest / 6;
    int n = wv * 96 + nt * 16 + (l & 15);
    int k = kt * 32 + (l >> 4) * 8 + 2 * r;
    float a = w[(size_t)n * DD + k];
    float b = w[(size_t)n * DD + k + 1];
    half2_t h = {(_Float16)a, (_Float16)b};
    wf[idx] = __builtin_bit_cast(unsigned int, h);
}

// ---------- gi = seq @ w_ih^T + b_ih ; M=65536, N=768, K=256 ----------
template <typename GiT>
__global__ __launch_bounds__(256)
void gemm_gi(const float* __restrict__ A,     // [M][256]
             const float* __restrict__ W,     // [768][256]
             const float* __restrict__ bias,  // [768]
             GiT* __restrict__ C)              // [M][768]
{
    __shared__ float As[32][68];
    __shared__ float Ws[32][68];
    const int tid = threadIdx.x;
    const int bm = blockIdx.y * 64;
    const int bn = blockIdx.x * 64;
    const int tm = (tid & 15) * 4;
    const int tn = (tid >> 4) * 4;
    const int r  = tid >> 3;
    const int c4 = (tid & 7) * 4;

    float acc[4][4] = {};

    for (int k0 = 0; k0 < 256; k0 += 32) {
#pragma unroll
        for (int rr = 0; rr < 64; rr += 32) {
            float4 a = *(const float4*)&A[(size_t)(bm + r + rr) * 256 + k0 + c4];
            As[c4 + 0][r + rr] = a.x;
            As[c4 + 1][r + rr] = a.y;
            As[c4 + 2][r + rr] = a.z;
            As[c4 + 3][r + rr] = a.w;
            float4 w = *(const float4*)&W[(size_t)(bn + r + rr) * 256 + k0 + c4];
            Ws[c4 + 0][r + rr] = w.x;
            Ws[c4 + 1][r + rr] = w.y;
            Ws[c4 + 2][r + rr] = w.z;
            Ws[c4 + 3][r + rr] = w.w;
        }
        __syncthreads();
#pragma unroll
        for (int kk = 0; kk < 32; ++kk) {
            float4 a = *(const float4*)&As[kk][tm];
            float4 w = *(const float4*)&Ws[kk][tn];
            float av[4] = {a.x, a.y, a.z, a.w};
            float wv[4] = {w.x, w.y, w.z, w.w};
#pragma unroll
            for (int i = 0; i < 4; ++i)
#pragma unroll
                for (int j = 0; j < 4; ++j)
                    acc[i][j] += av[i] * wv[j];
        }
        __syncthreads();
    }
#pragma unroll
    for (int i = 0; i < 4; ++i) {
        GiT* cp = C + (size_t)(bm + tm + i) * GG + bn + tn;
        store4(cp, acc[i][0] + bias[bn + tn + 0],
                   acc[i][1] + bias[bn + tn + 1],
                   acc[i][2] + bias[bn + tn + 2],
                   acc[i][3] + bias[bn + tn + 3]);
    }
}

// ---------- MFMA scan: 16 blocks x 2 batches, weights resident in VGPRs ----
template <typename GiT>
__global__ __launch_bounds__(512, 2)
void gru_scan(const GiT* __restrict__ gi,          // [T*B][768]
              const int* __restrict__ mask,         // [T*B]
              const float* __restrict__ h0,         // [B][256]
              const unsigned int* __restrict__ wf,  // packed B-fragments
              const float* __restrict__ b_hh,       // [768]
              float* __restrict__ out,              // [T*B][256]
              float* __restrict__ hfin)             // [B][256]
{
    const int blk = blockIdx.x;        // 0..15
    const int tid = threadIdx.x;       // 0..511
    const int wv  = tid >> 6;
    const int l   = tid & 63;

    __shared__ __align__(16) _Float16 hf[NB][HH];  // f16 state (A-matrix)
    __shared__ float gh2[GG][NB];                  // gh, rows interleaved
    __shared__ int   mlds[TT][NB];

    // ---- one-time: weights into 192 VGPRs (B-fragment order, coalesced) ----
    u32x4 w[6][8];
    {
        const u32x4* wp = (const u32x4*)wf;
#pragma unroll
        for (int nt = 0; nt < 6; ++nt)
#pragma unroll
            for (int kt = 0; kt < 8; ++kt)
                w[nt][kt] = wp[(size_t)((wv * 6 + nt) * 8 + kt) * 64 + l];
    }

    // ---- one-time: mask staging ----
    for (int i = tid; i < TT * NB; i += 512) {
        int t = i >> 1, b = i & 1;
        mlds[t][b] = mask[t * BB + blk * NB + b];
    }

    // ---- one-time: h0, gate-thread setup ----
    const int b  = tid >> 8;           // 0..1
    const int j  = tid & 255;          // 0..255
    const int bg = blk * NB + b;       // global batch
    float h_r = h0[bg * HH + j];
    hf[b][j] = (_Float16)h_r;
    const float bh0 = b_hh[j];
    const float bh1 = b_hh[j + HH];
    const float bh2 = b_hh[j + 2 * HH];

    // gi prefetch for t=0
    float ir, iz, inn;
    {
        const GiT* g0 = gi + (size_t)bg * GG + j;
        ir  = ldgi(g0);
        iz  = ldgi(g0 + HH);
        inn = ldgi(g0 + 2 * HH);
    }
    __syncthreads();
    int m = mlds[0][b];

    // A-fragment read address: row (l&15)%NB of hf, k-chunk (l>>4)
    const char* abase = (const char*)hf + ((l & 15) & (NB - 1)) * (HH * 2)
                                        + (l >> 4) * 16;

    for (int t = 0; t < TT; ++t) {
        // ---- issue gi prefetch for t+1 (consumed in gate phase) ----
        const int tn = (t + 1 < TT) ? t + 1 : t;
        float irn, izn, innn;
        {
            const GiT* gp = gi + ((size_t)tn * BB + bg) * GG + j;
            irn  = ldgi(gp);
            izn  = ldgi(gp + HH);
            innn = ldgi(gp + 2 * HH);
        }

        // ---- GEMV on matrix pipe: gh[NB][768] = H @ w_hh^T ----
        f32x4 acc[6] = {};
#pragma unroll
        for (int kt = 0; kt < 8; ++kt) {
            f16x8 a = *(const f16x8*)(abase + kt * 64);
#pragma unroll
            for (int nt = 0; nt < 6; ++nt)
                acc[nt] = __builtin_amdgcn_mfma_f32_16x16x32_f16(
                    a, __builtin_bit_cast(f16x8, w[nt][kt]), acc[nt], 0, 0, 0);
        }
        // scatter rows 0..NB-1 (lanes 0-15, regs q=0,1: row=(l>>4)*4+q)
        if (l < 16) {
#pragma unroll
            for (int nt = 0; nt < 6; ++nt) {
                int col = wv * 96 + nt * 16 + l;
                gh2[col][0] = acc[nt][0];
                gh2[col][1] = acc[nt][1];
            }
        }
        __syncthreads();  // gh visible; hf reads of this step done

        // ---- gates: one element per thread ----
        {
            float hr = gh2[j][b]          + bh0;
            float hz = gh2[j + HH][b]     + bh1;
            float hn = gh2[j + 2 * HH][b] + bh2;
            float r = 1.f / (1.f + __expf(-(ir + hr)));
            float z = 1.f / (1.f + __expf(-(iz + hz)));
            float e = __expf(2.f * (inn + r * hn));
            float n = 1.f - 2.f / (e + 1.f);
            float ht = (1.f - z) * n + z * h_r;
            out[((size_t)t * BB + bg) * HH + j] = m ? ht : 0.f;
            h_r = m ? ht : h_r;
            hf[b][j] = (_Float16)h_r;
        }
        ir = irn; iz = izn; inn = innn;
        m = mlds[tn][b];
        __syncthreads();  // hf update visible before next A-reads
    }
    hfin[bg * HH + j] = h_r;
}

extern "C" void kernel_launch(void* const* d_in, const int* in_sizes, int n_in,
                              void* d_out, int out_size, void* d_ws, size_t ws_size,
                              hipStream_t stream) {
    const float* seq  = (const float*)d_in[0];
    const int*   mask = (const int*)  d_in[1];
    const float* h0   = (const float*)d_in[2];
    const float* w_ih = (const float*)d_in[3];
    const float* w_hh = (const float*)d_in[4];
    const float* b_ih = (const float*)d_in[5];
    const float* b_hh = (const float*)d_in[6];

    float* out  = (float*)d_out;
    float* hfin = out + (size_t)TT * BB * HH;

    // workspace: [wf: 98304 u32][gi: T*B*768 f32 (or bf16 fallback)]
    const size_t wf_elems = (size_t)128 * GG;  // 98304
    unsigned int* wf = (unsigned int*)d_ws;
    const size_t gi_elems = (size_t)TT * BB * GG;
    const size_t need_f32 = wf_elems * 4 + gi_elems * 4;

    pack_w<<<(128 * GG) / 256, 256, 0, stream>>>(w_hh, wf);

    dim3 ggrid(GG / 64, (TT * BB) / 64);
    if (ws_size >= need_f32) {
        float* gip = (float*)d_ws + wf_elems;
        gemm_gi<float><<<ggrid, 256, 0, stream>>>(seq, w_ih, b_ih, gip);
        gru_scan<float><<<BB / NB, 512, 0, stream>>>(gip, mask, h0, wf, b_hh, out, hfin);
    } else {
        __hip_bfloat16* gip = (__hip_bfloat16*)((float*)d_ws + wf_elems);
        gemm_gi<__hip_bfloat16><<<ggrid, 256, 0, stream>>>(seq, w_ih, b_ih, gip);
        gru_scan<__hip_bfloat16><<<BB / NB, 512, 0, stream>>>(gip, mask, h0, wf, b_hh, out, hfin);
    }
}

// Round 4
// 1771.806 us; speedup vs baseline: 8.1481x; 1.5925x over previous
//
#include <hip/hip_runtime.h>
#include <hip/hip_bf16.h>

#define TT 2048
#define BB 32
#define DD 256
#define HH 256
#define GG 768   // 3*H

typedef _Float16 half2_t __attribute__((ext_vector_type(2)));

__device__ inline float fdot2(unsigned int w, unsigned int h, float acc) {
#if __has_builtin(__builtin_amdgcn_fdot2)
    return __builtin_amdgcn_fdot2(__builtin_bit_cast(half2_t, w),
                                  __builtin_bit_cast(half2_t, h), acc, false);
#else
    half2_t a = __builtin_bit_cast(half2_t, w);
    half2_t b = __builtin_bit_cast(half2_t, h);
    return acc + (float)a.x * (float)b.x + (float)a.y * (float)b.y;
#endif
}

// ---------- helpers for fp32/bf16 workspace storage of gi ----------
__device__ inline void store4(float* p, float a, float b, float c, float d) {
    *(float4*)p = make_float4(a, b, c, d);
}
__device__ inline void store4(__hip_bfloat16* p, float a, float b, float c, float d) {
    p[0] = __float2bfloat16(a);
    p[1] = __float2bfloat16(b);
    p[2] = __float2bfloat16(c);
    p[3] = __float2bfloat16(d);
}
__device__ inline float ldgi(const float* p) { return *p; }
__device__ inline float ldgi(const __hip_bfloat16* p) { return __bfloat162float(*p); }

// ---------- pack w_hh [768][256] f32 -> wpk [128][768] of f16x2 ----------
// wpk[q][j] = (f16(w_hh[j][2q]), f16(w_hh[j][2q+1]))
__global__ __launch_bounds__(256)
void pack_w(const float* __restrict__ w, unsigned int* __restrict__ wpk) {
    int i = blockIdx.x * 256 + threadIdx.x;  // 0 .. 98303
    int q = i / GG;
    int j = i - q * GG;
    float a = w[(size_t)j * DD + 2 * q];
    float b = w[(size_t)j * DD + 2 * q + 1];
    half2_t h = {(_Float16)a, (_Float16)b};
    wpk[i] = __builtin_bit_cast(unsigned int, h);
}

// ---------- gi = seq @ w_ih^T + b_ih ; M=65536, N=768, K=256 ----------
template <typename GiT>
__global__ __launch_bounds__(256)
void gemm_gi(const float* __restrict__ A,     // [M][256]
             const float* __restrict__ W,     // [768][256]
             const float* __restrict__ bias,  // [768]
             GiT* __restrict__ C)              // [M][768]
{
    __shared__ float As[32][68];
    __shared__ float Ws[32][68];
    const int tid = threadIdx.x;
    const int bm = blockIdx.y * 64;
    const int bn = blockIdx.x * 64;
    const int tm = (tid & 15) * 4;
    const int tn = (tid >> 4) * 4;
    const int r  = tid >> 3;
    const int c4 = (tid & 7) * 4;

    float acc[4][4] = {};

    for (int k0 = 0; k0 < 256; k0 += 32) {
#pragma unroll
        for (int rr = 0; rr < 64; rr += 32) {
            float4 a = *(const float4*)&A[(size_t)(bm + r + rr) * 256 + k0 + c4];
            As[c4 + 0][r + rr] = a.x;
            As[c4 + 1][r + rr] = a.y;
            As[c4 + 2][r + rr] = a.z;
            As[c4 + 3][r + rr] = a.w;
            float4 w = *(const float4*)&W[(size_t)(bn + r + rr) * 256 + k0 + c4];
            Ws[c4 + 0][r + rr] = w.x;
            Ws[c4 + 1][r + rr] = w.y;
            Ws[c4 + 2][r + rr] = w.z;
            Ws[c4 + 3][r + rr] = w.w;
        }
        __syncthreads();
#pragma unroll
        for (int kk = 0; kk < 32; ++kk) {
            float4 a = *(const float4*)&As[kk][tm];
            float4 w = *(const float4*)&Ws[kk][tn];
            float av[4] = {a.x, a.y, a.z, a.w};
            float wv[4] = {w.x, w.y, w.z, w.w};
#pragma unroll
            for (int i = 0; i < 4; ++i)
#pragma unroll
                for (int j = 0; j < 4; ++j)
                    acc[i][j] += av[i] * wv[j];
        }
        __syncthreads();
    }
#pragma unroll
    for (int i = 0; i < 4; ++i) {
        GiT* cp = C + (size_t)(bm + tm + i) * GG + bn + tn;
        store4(cp, acc[i][0] + bias[bn + tn + 0],
                   acc[i][1] + bias[bn + tn + 1],
                   acc[i][2] + bias[bn + tn + 2],
                   acc[i][3] + bias[bn + tn + 3]);
    }
}

// ---------- sequential scan: 1 workgroup per batch row, mask-skip ----------
// Thread j holds w_hh row j (256 weights) as 128 packed f16x2 in VGPRs,
// pinned there by an asm fence (round-2 showed the compiler remats the
// loads otherwise: VGPR_Count was 84 < 128).
template <typename GiT>
__global__ __launch_bounds__(768, 3)
void gru_scan(const GiT* __restrict__ gi,          // [T*B][768]
              const int* __restrict__ mask,         // [T*B]
              const float* __restrict__ h0,         // [B][256]
              const unsigned int* __restrict__ wpk, // [128][768] f16x2
              const float* __restrict__ b_hh,       // [768]
              float* __restrict__ out,              // [T*B][256]
              float* __restrict__ hfin)             // [B][256]
{
    const int b = blockIdx.x;
    const int j = threadIdx.x;  // 0..767
    __shared__ __align__(16) _Float16 hhalf[HH];  // f16 state for the GEMV
    __shared__ float gh_lds[GG];
    __shared__ int mlds[TT];

    // --- one-time: weights into 128 VGPRs (coalesced across lanes) ---
    unsigned int w[128];
#pragma unroll
    for (int q = 0; q < 128; ++q)
        w[q] = wpk[q * GG + j];
#pragma unroll
    for (int q = 0; q < 128; ++q)
        asm volatile("" : "+v"(w[q]));  // forbid rematerialization

    for (int t = j; t < TT; t += GG)
        mlds[t] = mask[t * BB + b];

    float h_r = 0.f;
    if (j < HH) {
        h_r = h0[b * HH + j];
        hhalf[j] = (_Float16)h_r;
    }
    const float bhh = b_hh[j];
    __syncthreads();

    const uint4* hu4 = (const uint4*)hhalf;

    for (int t = 0; t < TT; ++t) {
        if (mlds[t]) {
            // gi loads issued now, consumed in the gate phase (~1500 cyc
            // later: GEMV + barrier cover HBM latency)
            float ir = 0.f, iz = 0.f, inn = 0.f;
            if (j < HH) {
                const GiT* gtb = gi + ((size_t)t * BB + b) * GG;
                ir  = ldgi(gtb + j);
                iz  = ldgi(gtb + j + HH);
                inn = ldgi(gtb + j + 2 * HH);
            }

            // GEMV: gh[j] = b_hh[j] + sum_k w_hh[j][k] * h[k]
            float a0 = bhh, a1 = 0.f, a2 = 0.f, a3 = 0.f;
#pragma unroll
            for (int q4 = 0; q4 < 32; ++q4) {
                uint4 hv = hu4[q4];  // wave-uniform -> LDS broadcast
                a0 = fdot2(w[4 * q4 + 0], hv.x, a0);
                a1 = fdot2(w[4 * q4 + 1], hv.y, a1);
                a2 = fdot2(w[4 * q4 + 2], hv.z, a2);
                a3 = fdot2(w[4 * q4 + 3], hv.w, a3);
            }
            gh_lds[j] = (a0 + a1) + (a2 + a3);
            __syncthreads();  // gh visible; hhalf reads done

            if (j < HH) {
                float hr = gh_lds[j];
                float hz = gh_lds[j + HH];
                float hn = gh_lds[j + 2 * HH];
                float r = 1.f / (1.f + __expf(-(ir + hr)));
                float z = 1.f / (1.f + __expf(-(iz + hz)));
                float e = __expf(2.f * (inn + r * hn));
                float n = 1.f - 2.f / (e + 1.f);
                float ht = (1.f - z) * n + z * h_r;
                out[((size_t)t * BB + b) * HH + j] = ht;
                h_r = ht;
                hhalf[j] = (_Float16)ht;
            }
            __syncthreads();  // h update visible before next GEMV
        } else {
            // masked step: h unchanged, output row is exactly zero;
            // no GEMV, no gi read, no barriers (branch is block-uniform)
            if (j < HH)
                out[((size_t)t * BB + b) * HH + j] = 0.f;
        }
    }
    if (j < HH) hfin[b * HH + j] = h_r;
}

extern "C" void kernel_launch(void* const* d_in, const int* in_sizes, int n_in,
                              void* d_out, int out_size, void* d_ws, size_t ws_size,
                              hipStream_t stream) {
    const float* seq  = (const float*)d_in[0];
    const int*   mask = (const int*)  d_in[1];
    const float* h0   = (const float*)d_in[2];
    const float* w_ih = (const float*)d_in[3];
    const float* w_hh = (const float*)d_in[4];
    const float* b_ih = (const float*)d_in[5];
    const float* b_hh = (const float*)d_in[6];

    float* out  = (float*)d_out;
    float* hfin = out + (size_t)TT * BB * HH;

    // workspace layout: [wpk: 128*768 u32][gi: T*B*768 f32 (or bf16 fallback)]
    const size_t wpk_elems = (size_t)128 * GG;
    unsigned int* wpk = (unsigned int*)d_ws;
    const size_t gi_elems = (size_t)TT * BB * GG;
    const size_t need_f32 = wpk_elems * 4 + gi_elems * 4;

    pack_w<<<(128 * GG) / 256, 256, 0, stream>>>(w_hh, wpk);

    dim3 ggrid(GG / 64, (TT * BB) / 64);
    if (ws_size >= need_f32) {
        float* gip = (float*)d_ws + wpk_elems;
        gemm_gi<float><<<ggrid, 256, 0, stream>>>(seq, w_ih, b_ih, gip);
        gru_scan<float><<<BB, GG, 0, stream>>>(gip, mask, h0, wpk, b_hh, out, hfin);
    } else {
        __hip_bfloat16* gip = (__hip_bfloat16*)((float*)d_ws + wpk_elems);
        gemm_gi<__hip_bfloat16><<<ggrid, 256, 0, stream>>>(seq, w_ih, b_ih, gip);
        gru_scan<__hip_bfloat16><<<BB, GG, 0, stream>>>(gip, mask, h0, wpk, b_hh, out, hfin);
    }
}